// Round 22
// baseline (298.538 us; speedup 1.0000x reference)
//
#include <hip/hip_runtime.h>
#include <hip/hip_bf16.h>

#define B_ 4
#define T_ 2048
#define D_ 1024
#define H_ 16

typedef __attribute__((ext_vector_type(8))) short short8;
typedef __attribute__((ext_vector_type(4))) float f32x4;

__device__ __forceinline__ unsigned short f2bf(float f) {
  unsigned int u = __float_as_uint(f);
  u += 0x7FFFu + ((u >> 16) & 1u);
  return (unsigned short)(u >> 16);
}

__device__ __forceinline__ void gload_lds16(const void* g, void* l) {
  __builtin_amdgcn_global_load_lds(
      (const __attribute__((address_space(1))) void*)g,
      (__attribute__((address_space(3))) void*)l, 16, 0, 0);
}

// XCD-aware bijective remap for (8, 64) grids: groups the 8 x-blocks of each
// y-panel onto one XCD (hw xcd = linear_id % 8). Returns (x, y).
__device__ __forceinline__ void xcd_remap(int bx, int by, int& x, int& y) {
  const int L = by * 8 + bx;
  const int c = L & 7, rest = L >> 3;
  x = rest & 7;
  y = (rest >> 3) * 8 + c;
}

// ONE launch for all preprocessing:
// blocks [0, 28672): fp32->bf16 conversions (q/k/v then 4 weights, flat float4
// index); blocks [28672, 28928): mask -> wave-shaped VCC u64s
// (bit(lane=lhi*16+l15) = mask(q=g*16+l15, kv=kvb*64+nt*16+lhi*4+r) != 0).
__global__ __launch_bounds__(256) void prep_all(
    const float* __restrict__ q, const float* __restrict__ k,
    const float* __restrict__ v, const float* __restrict__ w0,
    const float* __restrict__ w1, const float* __restrict__ w2,
    const float* __restrict__ w3, unsigned short* __restrict__ oq,
    unsigned short* __restrict__ ok, unsigned short* __restrict__ ov,
    unsigned short* __restrict__ o0, unsigned short* __restrict__ o1,
    unsigned short* __restrict__ o2, unsigned short* __restrict__ o3,
    const int* __restrict__ mask, unsigned long long* __restrict__ mv) {
  const unsigned bid = blockIdx.x;
  if (bid < 28672u) {
    const unsigned i = bid * 256 + threadIdx.x;
    const float* src;
    unsigned short* dst;
    unsigned off;
    if (i < 6291456u) {
      const unsigned t = i >> 21;
      off = i & 2097151u;
      src = (t == 0) ? q : (t == 1) ? k : v;
      dst = (t == 0) ? oq : (t == 1) ? ok : ov;
    } else {
      const unsigned j = i - 6291456u;
      const unsigned t = j >> 18;
      off = j & 262143u;
      src = (t == 0) ? w0 : (t == 1) ? w1 : (t == 2) ? w2 : w3;
      dst = (t == 0) ? o0 : (t == 1) ? o1 : (t == 2) ? o2 : o3;
    }
    float4 x = reinterpret_cast<const float4*>(src)[off];
    ushort4 o;
    o.x = f2bf(x.x); o.y = f2bf(x.y); o.z = f2bf(x.z); o.w = f2bf(x.w);
    reinterpret_cast<ushort4*>(dst)[off] = o;
  } else {
    const unsigned pid = bid - 28672u;  // [0, 256)
    const int qt = pid & 31, b = (pid >> 5) & 3, kvh = pid >> 7;
    const int lane = threadIdx.x & 63, wave = threadIdx.x >> 6;
    const int lhi = lane >> 4, l15 = lane & 15;
    const int qq = qt * 64 + wave * 16 + l15;
    const int* mrow = mask + ((size_t)b * 2048 + qq) * 2048;
    unsigned long long* outw =
        mv + (((size_t)(b * 32 + qt) * 4 + wave) << 9) + kvh * 256;
#pragma unroll 2
    for (int i = 0; i < 64; ++i) {
      const int kvb = i >> 2, nt = i & 3;
      const int kv = (kvh * 16 + kvb) * 64 + nt * 16 + lhi * 4;
      int4 mvv = *(const int4*)(mrow + kv);
      unsigned long long b0 = __ballot(mvv.x != 0);
      unsigned long long b1 = __ballot(mvv.y != 0);
      unsigned long long b2 = __ballot(mvv.z != 0);
      unsigned long long b3 = __ballot(mvv.w != 0);
      if (lane == 0) {
        unsigned long long* o = outw + kvb * 16 + nt * 4;
        o[0] = b0; o[1] = b1; o[2] = b2; o[3] = b3;
      }
    }
  }
}

// C = A(MxK) * B(NxK)^T + bias.  MODE 0: Q head-layout bf16 (*0.125*log2e)
// MODE 1: K head-layout bf16.  MODE 2: V transposed head-layout bf16.
// MODE 3: fp32 output.  Single-buffered m97 2-barrier structure with BK=128
// (round-19 proven).
template <int MODE>
__global__ __launch_bounds__(256, 2) void gemm_bt(
    const unsigned short* __restrict__ A, const unsigned short* __restrict__ Bm,
    const float* __restrict__ bias, void* __restrict__ Cout, int M, int K_) {
  __shared__ unsigned short lA[128 * 128];
  __shared__ unsigned short lB[128 * 128];
  const int tid = threadIdx.x, lane = tid & 63, wave = tid >> 6;
  const int l15 = lane & 15, lhi = lane >> 4;
  int bx, by;
  xcd_remap(blockIdx.x, blockIdx.y, bx, by);  // 8 n-blocks of a y-panel -> 1 XCD
  const int m0 = by * 128, n0 = bx * 128;
  const int wr = wave >> 1, wc = wave & 1;

  f32x4 acc[4][4];
#pragma unroll
  for (int i = 0; i < 4; ++i)
#pragma unroll
    for (int j = 0; j < 4; ++j) acc[i][j] = (f32x4)0.0f;

  // staging: 2048 chunks of 16B per matrix per K-step, 8 per lane.
  // Pre-swizzled global source, linear LDS dest.
  unsigned aoff[8], ldo[8];
#pragma unroll
  for (int i = 0; i < 8; ++i) {
    const int cid = i * 256 + tid;
    const int row = cid >> 4, cs = cid & 15;
    const int cg = cs ^ (row & 15);
    aoff[i] = (unsigned)row * (unsigned)(K_ * 2) + cg * 16;
    ldo[i] = (unsigned)cid * 16;
  }
  const char* ap = (const char*)(A + (size_t)m0 * K_);
  const char* bp = (const char*)(Bm + (size_t)n0 * K_);

  const int KT = K_ >> 7;  // 128-wide K-steps
  for (int kt = 0; kt < KT; ++kt) {
#pragma unroll
    for (int i = 0; i < 8; ++i) {
      gload_lds16(ap + aoff[i], (char*)lA + ldo[i]);
      gload_lds16(bp + aoff[i], (char*)lB + ldo[i]);
    }
    ap += 256; bp += 256;
    __syncthreads();  // drains staging vmcnt
#pragma unroll
    for (int ks = 0; ks < 4; ++ks) {
      short8 af[4], bfr[4];
#pragma unroll
      for (int mt = 0; mt < 4; ++mt) {
        const int row = wr * 64 + mt * 16 + l15;
        const int byteoff = (ks * 64 + lhi * 16) ^ ((row & 15) << 4);
        af[mt] = *(const short8*)((const char*)lA + row * 256 + byteoff);
      }
#pragma unroll
      for (int nt = 0; nt < 4; ++nt) {
        const int row = wc * 64 + nt * 16 + l15;
        const int byteoff = (ks * 64 + lhi * 16) ^ ((row & 15) << 4);
        bfr[nt] = *(const short8*)((const char*)lB + row * 256 + byteoff);
      }
#pragma unroll
      for (int mt = 0; mt < 4; ++mt)
#pragma unroll
        for (int nt = 0; nt < 4; ++nt)
          acc[mt][nt] = __builtin_amdgcn_mfma_f32_16x16x32_bf16(af[mt], bfr[nt], acc[mt][nt], 0, 0, 0);
    }
    __syncthreads();  // safe to overwrite tile next iter
  }

#pragma unroll
  for (int mt = 0; mt < 4; ++mt) {
#pragma unroll
    for (int nt = 0; nt < 4; ++nt) {
      const int n = n0 + wc * 64 + nt * 16 + l15;
      const float bv = bias[n];
#pragma unroll
      for (int r = 0; r < 4; ++r) {
        const int m = m0 + wr * 64 + mt * 16 + lhi * 4 + r;
        float v = acc[mt][nt][r] + bv;
        if (MODE == 0 || MODE == 1) {
          if (MODE == 0) v *= 0.18033688011112042f;  // 0.125 * log2(e)
          const int b = m >> 11, t = m & 2047;
          const int h = n >> 6, dk = n & 63;
          ((unsigned short*)Cout)[(((size_t)(b * 16 + h) * 2048 + t) << 6) + dk] = f2bf(v);
        } else if (MODE == 2) {
          const int b = m >> 11, t = m & 2047;
          const int h = n >> 6, dv = n & 63;
          ((unsigned short*)Cout)[((size_t)((b * 16 + h) * 64 + dv) << 11) + t] = f2bf(v);
        } else {
          ((float*)Cout)[(size_t)m * 1024 + n] = v;
        }
      }
    }
  }
}

// flash attention (no-max softmax, exp2-domain): grid (T/256, B*H), 8 waves,
// 32 q rows per wave (2 subtiles of 16), disjoint lP per (wave, sub).
// T14 async-STAGE split (round-16 proven, 94us): K/V tile kb+1 loaded into
// REGISTERS at iteration top (compiler-managed waitcnt), full iteration of
// compute hides HBM latency, then barrier / ds_write / barrier.
__global__ __launch_bounds__(512, 2) void attn_kernel(
    const unsigned short* __restrict__ Qh, const unsigned short* __restrict__ Kh,
    const unsigned short* __restrict__ VTh, const unsigned long long* __restrict__ maskv,
    unsigned short* __restrict__ Xout) {
  __shared__ unsigned short lK[64 * 64];
  __shared__ unsigned short lVT[64 * 64];
  __shared__ unsigned short lP[8][2][16 * 64];
  const int tid = threadIdx.x, lane = tid & 63, wave = tid >> 6;
  const int l15 = lane & 15, lhi = lane >> 4;
  int qt, bh;
  xcd_remap(blockIdx.x, blockIdx.y, qt, bh);  // 8 q-tiles of a head -> 1 XCD
  const int b = bh >> 4, h = bh & 15;
  const int qbase = qt * 256 + wave * 32;  // wave's 32 q rows

  // Q fragments (B operand of swapped QK^T): Q[q=qbase+sub*16+l15][k=lhi*8+j]
  short8 qf[2][2];
#pragma unroll
  for (int sub = 0; sub < 2; ++sub) {
    const size_t qb = ((size_t)bh * 2048 + (qbase + sub * 16 + l15)) * 64 + lhi * 8;
    qf[sub][0] = *(const short8*)(Qh + qb);
    qf[sub][1] = *(const short8*)(Qh + qb + 32);
  }
  f32x4 oacc[2][4];  // O[sub][q=lhi*4+r][dv=nt*16+l15]
#pragma unroll
  for (int sub = 0; sub < 2; ++sub)
#pragma unroll
    for (int nt = 0; nt < 4; ++nt) oacc[sub][nt] = (f32x4)0.0f;
  f32x4 lacc0 = (f32x4)0.0f, lacc1 = (f32x4)0.0f;  // row sums via ones-col MFMA

  short8 ones8;
#pragma unroll
  for (int j = 0; j < 8; ++j) ones8[j] = (short)0x3F80;  // bf16 1.0

  // staging: one K chunk + one VT chunk per lane (512 lanes = 512 chunks each)
  const int cl = tid;  // chunk id
  const int crow = cl >> 3, cg = (cl & 7) ^ (crow & 7);
  const unsigned koff = (unsigned)(crow * 128 + cg * 16);   // K row-major [64][64]
  const unsigned voff = (unsigned)(crow * 4096 + cg * 16);  // VT row stride 2048 bf16
  char* const ldK = (char*)lK + tid * 16;   // same layout the DMA variant used
  char* const ldV = (char*)lVT + tid * 16;
  const char* kp = (const char*)(Kh + (size_t)bh * (2048 * 64));
  const char* vp = (const char*)(VTh + (size_t)bh * (64 * 2048));
  // readfirstlane keeps mask pointers provably wave-uniform (s_load -> SGPR
  // pairs, required by the "s" asm constraint below).
  const int wv = __builtin_amdgcn_readfirstlane(wave);
  const unsigned long long* mk0 =
      maskv + ((size_t)(b * 128 + qt * 16 + wv * 2) << 9);
  const unsigned long long* mk1 = mk0 + 512;

  // prologue: tile 0 via regs -> LDS (compiler inserts the vmcnt wait at the
  // register use inside the ds_write)
  {
    uint4 kreg = *(const uint4*)(kp + koff);
    uint4 vreg = *(const uint4*)(vp + voff);
    *(uint4*)ldK = kreg;
    *(uint4*)ldV = vreg;
  }
  __syncthreads();
  const char* kpn = kp + 8192;
  const char* vpn = vp + 128;

  const float ninf = __int_as_float(0xFF800000u);
  for (int kb = 0; kb < 32; ++kb) {
    // issue-early: next tile into registers; consumed only at the ds_write
    // after the end-of-iteration barrier -> full body hides HBM latency.
    uint4 kreg, vreg;
    if (kb < 31) {
      kreg = *(const uint4*)(kpn + koff);
      vreg = *(const uint4*)(vpn + voff);
      kpn += 8192; vpn += 128;
    }

    // S^T = K Q^T for both subtiles: each kf read feeds 2 MFMA.
    // lane holds S[sub][kv=nt*16+lhi*4+r][q=l15] (log2-domain)
    f32x4 s[2][4];
    __builtin_amdgcn_s_setprio(1);
#pragma unroll
    for (int nt = 0; nt < 4; ++nt) {
      f32x4 a0 = (f32x4)0.0f, a1 = (f32x4)0.0f;
#pragma unroll
      for (int ks = 0; ks < 2; ++ks) {
        const int row = nt * 16 + l15;
        const int byteoff = (ks * 64 + lhi * 16) ^ ((row & 7) << 4);
        short8 kf = *(const short8*)((const char*)lK + row * 128 + byteoff);
        a0 = __builtin_amdgcn_mfma_f32_16x16x32_bf16(kf, qf[0][ks], a0, 0, 0, 0);
        a1 = __builtin_amdgcn_mfma_f32_16x16x32_bf16(kf, qf[1][ks], a1, 0, 0, 0);
      }
      s[0][nt] = a0;
      s[1][nt] = a1;
    }
    __builtin_amdgcn_s_setprio(0);

    // mask-select (-inf) + exp2 + pack + P->LDS for BOTH subtiles (PV follows)
#pragma unroll
    for (int sub = 0; sub < 2; ++sub) {
      const unsigned long long* mk = (sub == 0) ? mk0 : mk1;
      uint2 pu[4];
#pragma unroll
      for (int nt = 0; nt < 4; ++nt) {
        float p0, p1, p2, p3;
        {
          float sm;
          asm("v_cndmask_b32 %0, %1, %2, %3"
              : "=v"(sm) : "v"(ninf), "v"(s[sub][nt][0]), "s"(mk[nt * 4 + 0]));
          p0 = __builtin_amdgcn_exp2f(sm);
          asm("v_cndmask_b32 %0, %1, %2, %3"
              : "=v"(sm) : "v"(ninf), "v"(s[sub][nt][1]), "s"(mk[nt * 4 + 1]));
          p1 = __builtin_amdgcn_exp2f(sm);
          asm("v_cndmask_b32 %0, %1, %2, %3"
              : "=v"(sm) : "v"(ninf), "v"(s[sub][nt][2]), "s"(mk[nt * 4 + 2]));
          p2 = __builtin_amdgcn_exp2f(sm);
          asm("v_cndmask_b32 %0, %1, %2, %3"
              : "=v"(sm) : "v"(ninf), "v"(s[sub][nt][3]), "s"(mk[nt * 4 + 3]));
          p3 = __builtin_amdgcn_exp2f(sm);
        }
        unsigned int lo, hi;
        asm("v_cvt_pk_bf16_f32 %0, %1, %2" : "=v"(lo) : "v"(p0), "v"(p1));
        asm("v_cvt_pk_bf16_f32 %0, %1, %2" : "=v"(hi) : "v"(p2), "v"(p3));
        pu[nt].x = lo;
        pu[nt].y = hi;
      }
      unsigned short* lPw = lP[wave][sub];
      {
        const int swz = (l15 & 7) << 4;
        char* rowp = (char*)lPw + l15 * 128;
#pragma unroll
        for (int nt = 0; nt < 4; ++nt)
          *(uint2*)(rowp + ((nt * 32 + lhi * 8) ^ swz)) = pu[nt];
      }
    }
    mk0 += 16;
    mk1 += 16;

    // PV: shared vf reads — each V fragment feeds both subtiles
    __builtin_amdgcn_s_setprio(1);
#pragma unroll
    for (int ks = 0; ks < 2; ++ks) {
      const int pbyte = (ks * 64 + lhi * 16) ^ ((l15 & 7) << 4);
      short8 pf0 = *(const short8*)((const char*)lP[wave][0] + l15 * 128 + pbyte);
      short8 pf1 = *(const short8*)((const char*)lP[wave][1] + l15 * 128 + pbyte);
      lacc0 = __builtin_amdgcn_mfma_f32_16x16x32_bf16(pf0, ones8, lacc0, 0, 0, 0);
      lacc1 = __builtin_amdgcn_mfma_f32_16x16x32_bf16(pf1, ones8, lacc1, 0, 0, 0);
#pragma unroll
      for (int nt = 0; nt < 4; ++nt) {
        const int vrow = nt * 16 + l15;
        const int vbyte = (ks * 64 + lhi * 16) ^ ((vrow & 7) << 4);
        short8 vf = *(const short8*)((const char*)lVT + vrow * 128 + vbyte);
        oacc[0][nt] = __builtin_amdgcn_mfma_f32_16x16x32_bf16(pf0, vf, oacc[0][nt], 0, 0, 0);
        oacc[1][nt] = __builtin_amdgcn_mfma_f32_16x16x32_bf16(pf1, vf, oacc[1][nt], 0, 0, 0);
      }
    }
    __builtin_amdgcn_s_setprio(0);

    if (kb < 31) {
      __syncthreads();     // all waves done READING tile kb
      *(uint4*)ldK = kreg; // write tile kb+1 (vmcnt wait auto-inserted here)
      *(uint4*)ldV = vreg;
      __syncthreads();     // writes visible to all waves
    }
  }

#pragma unroll
  for (int sub = 0; sub < 2; ++sub) {
#pragma unroll
    for (int r = 0; r < 4; ++r) {
      const float l = (sub == 0) ? lacc0[r] : lacc1[r];
      const float inv = l > 0.0f ? 1.0f / l : 0.0f;
      const int t = qbase + sub * 16 + lhi * 4 + r;
      unsigned short* dst = Xout + ((size_t)(b * 2048 + t)) * 1024 + h * 64;
#pragma unroll
      for (int nt = 0; nt < 4; ++nt) dst[nt * 16 + l15] = f2bf(oacc[sub][nt][r] * inv);
    }
  }
}

extern "C" void kernel_launch(void* const* d_in, const int* in_sizes, int n_in,
                              void* d_out, int out_size, void* d_ws, size_t ws_size,
                              hipStream_t stream) {
  const float* query = (const float*)d_in[0];
  const float* key = (const float*)d_in[1];
  const float* value = (const float*)d_in[2];
  const int* mask = (const int*)d_in[3];
  const float* Wq = (const float*)d_in[4];
  const float* bq = (const float*)d_in[5];
  const float* Wk = (const float*)d_in[6];
  const float* bk = (const float*)d_in[7];
  const float* Wv = (const float*)d_in[8];
  const float* bv = (const float*)d_in[9];
  const float* Wo = (const float*)d_in[10];
  const float* bo = (const float*)d_in[11];
  float* out = (float*)d_out;

  char* ws = (char*)d_ws;
  size_t off = 0;
  auto alloc = [&](size_t bytes) {
    char* p = ws + off;
    off += (bytes + 255) & ~(size_t)255;
    return p;
  };
  const size_t NE = (size_t)B_ * T_ * D_;  // 8388608
  unsigned short* qb = (unsigned short*)alloc(NE * 2);  // also reused as X
  unsigned short* kb = (unsigned short*)alloc(NE * 2);
  unsigned short* vb = (unsigned short*)alloc(NE * 2);
  unsigned short* wqb = (unsigned short*)alloc((size_t)1024 * 1024 * 2);
  unsigned short* wkb = (unsigned short*)alloc((size_t)1024 * 1024 * 2);
  unsigned short* wvb = (unsigned short*)alloc((size_t)1024 * 1024 * 2);
  unsigned short* wob = (unsigned short*)alloc((size_t)1024 * 1024 * 2);
  unsigned short* Qh = (unsigned short*)alloc(NE * 2);
  unsigned short* Kh = (unsigned short*)alloc(NE * 2);
  unsigned short* VTh = (unsigned short*)alloc(NE * 2);
  unsigned long long* pmw = (unsigned long long*)alloc((size_t)B_ * 32 * 4 * 512 * 8);

  // all fp32->bf16 conversions + mask packing in ONE launch
  prep_all<<<28928, 256, 0, stream>>>(query, key, value, Wq, Wk, Wv, Wo,
                                      qb, kb, vb, wqb, wkb, wvb, wob,
                                      mask, pmw);

  const int M = B_ * T_;  // 8192
  dim3 ggrid(8, 64);
  gemm_bt<0><<<ggrid, 256, 0, stream>>>(qb, wqb, bq, Qh, M, 1024);
  gemm_bt<1><<<ggrid, 256, 0, stream>>>(kb, wkb, bk, Kh, M, 1024);
  gemm_bt<2><<<ggrid, 256, 0, stream>>>(vb, wvb, bv, VTh, M, 1024);

  dim3 agrid(T_ / 256, B_ * H_);
  attn_kernel<<<agrid, 512, 0, stream>>>(Qh, Kh, VTh, pmw, qb);

  dim3 ogrid(8, 64);
  gemm_bt<3><<<ogrid, 256, 0, stream>>>(qb, wob, bo, out, M, 1024);
}

// Round 23
// 237.407 us; speedup vs baseline: 1.2575x; 1.2575x over previous
//
#include <hip/hip_runtime.h>
#include <hip/hip_bf16.h>

#define B_ 4
#define T_ 2048
#define D_ 1024
#define H_ 16

typedef __attribute__((ext_vector_type(8))) short short8;
typedef __attribute__((ext_vector_type(4))) float f32x4;

__device__ __forceinline__ unsigned short f2bf(float f) {
  unsigned int u = __float_as_uint(f);
  u += 0x7FFFu + ((u >> 16) & 1u);
  return (unsigned short)(u >> 16);
}

__device__ __forceinline__ void gload_lds16(const void* g, void* l) {
  __builtin_amdgcn_global_load_lds(
      (const __attribute__((address_space(1))) void*)g,
      (__attribute__((address_space(3))) void*)l, 16, 0, 0);
}

// XCD-aware bijective remap for (8, 64) grids: groups the 8 x-blocks of each
// y-panel onto one XCD (hw xcd = linear_id % 8). Returns (x, y).
__device__ __forceinline__ void xcd_remap(int bx, int by, int& x, int& y) {
  const int L = by * 8 + bx;
  const int c = L & 7, rest = L >> 3;
  x = rest & 7;
  y = (rest >> 3) * 8 + c;
}

// All 7 fp32->bf16 conversions in ONE flat-indexed launch:
// [0,3*2^21): q/k/v (2^21 float4 each); then 4 weights (2^18 float4 each).
__global__ __launch_bounds__(256) void cvt_all(
    const float* __restrict__ q, const float* __restrict__ k,
    const float* __restrict__ v, const float* __restrict__ w0,
    const float* __restrict__ w1, const float* __restrict__ w2,
    const float* __restrict__ w3, unsigned short* __restrict__ oq,
    unsigned short* __restrict__ ok, unsigned short* __restrict__ ov,
    unsigned short* __restrict__ o0, unsigned short* __restrict__ o1,
    unsigned short* __restrict__ o2, unsigned short* __restrict__ o3) {
  const unsigned i = blockIdx.x * 256 + threadIdx.x;
  const float* src;
  unsigned short* dst;
  unsigned off;
  if (i < 6291456u) {
    const unsigned t = i >> 21;
    off = i & 2097151u;
    src = (t == 0) ? q : (t == 1) ? k : v;
    dst = (t == 0) ? oq : (t == 1) ? ok : ov;
  } else {
    const unsigned j = i - 6291456u;
    const unsigned t = j >> 18;
    off = j & 262143u;
    src = (t == 0) ? w0 : (t == 1) ? w1 : (t == 2) ? w2 : w3;
    dst = (t == 0) ? o0 : (t == 1) ? o1 : (t == 2) ? o2 : o3;
  }
  float4 x = reinterpret_cast<const float4*>(src)[off];
  ushort4 o;
  o.x = f2bf(x.x); o.y = f2bf(x.y); o.z = f2bf(x.z); o.w = f2bf(x.w);
  reinterpret_cast<ushort4*>(dst)[off] = o;
}

// Pre-permute mask into wave-shaped VCC u64s, group g = b*128 + (q>>4):
// bit(lane=lhi*16+l15) = mask(q, kv=kvb*64+nt*16+lhi*4+r) != 0
__global__ __launch_bounds__(256) void pack_mask_v(const int* __restrict__ mask,
                                                   unsigned long long* __restrict__ mv) {
  const int lane = threadIdx.x & 63, wave = threadIdx.x >> 6;
  const int lhi = lane >> 4, l15 = lane & 15;
  const int qt = blockIdx.x, b = blockIdx.y, kvh = blockIdx.z;
  const int q = qt * 64 + wave * 16 + l15;
  const int* mrow = mask + ((size_t)b * 2048 + q) * 2048;
  unsigned long long* outw = mv + (((size_t)(b * 32 + qt) * 4 + wave) << 9) + kvh * 256;
#pragma unroll 2
  for (int i = 0; i < 64; ++i) {
    const int kvb = i >> 2, nt = i & 3;
    const int kv = (kvh * 16 + kvb) * 64 + nt * 16 + lhi * 4;
    int4 v = *(const int4*)(mrow + kv);
    unsigned long long b0 = __ballot(v.x != 0);
    unsigned long long b1 = __ballot(v.y != 0);
    unsigned long long b2 = __ballot(v.z != 0);
    unsigned long long b3 = __ballot(v.w != 0);
    if (lane == 0) {
      unsigned long long* o = outw + kvb * 16 + nt * 4;
      o[0] = b0; o[1] = b1; o[2] = b2; o[3] = b3;
    }
  }
}

// C = A(MxK) * B(NxK)^T + bias.  MODE 0: Q head-layout bf16 (*0.125*log2e)
// MODE 1: K head-layout bf16.  MODE 2: V transposed head-layout bf16.
// MODE 3: fp32 output.  Single-buffered m97 2-barrier structure with BK=128
// (round-19 proven).
template <int MODE>
__global__ __launch_bounds__(256, 2) void gemm_bt(
    const unsigned short* __restrict__ A, const unsigned short* __restrict__ Bm,
    const float* __restrict__ bias, void* __restrict__ Cout, int M, int K_) {
  __shared__ unsigned short lA[128 * 128];
  __shared__ unsigned short lB[128 * 128];
  const int tid = threadIdx.x, lane = tid & 63, wave = tid >> 6;
  const int l15 = lane & 15, lhi = lane >> 4;
  int bx, by;
  xcd_remap(blockIdx.x, blockIdx.y, bx, by);  // 8 n-blocks of a y-panel -> 1 XCD
  const int m0 = by * 128, n0 = bx * 128;
  const int wr = wave >> 1, wc = wave & 1;

  f32x4 acc[4][4];
#pragma unroll
  for (int i = 0; i < 4; ++i)
#pragma unroll
    for (int j = 0; j < 4; ++j) acc[i][j] = (f32x4)0.0f;

  // staging: 2048 chunks of 16B per matrix per K-step, 8 per lane.
  // Pre-swizzled global source, linear LDS dest.
  unsigned aoff[8], ldo[8];
#pragma unroll
  for (int i = 0; i < 8; ++i) {
    const int cid = i * 256 + tid;
    const int row = cid >> 4, cs = cid & 15;
    const int cg = cs ^ (row & 15);
    aoff[i] = (unsigned)row * (unsigned)(K_ * 2) + cg * 16;
    ldo[i] = (unsigned)cid * 16;
  }
  const char* ap = (const char*)(A + (size_t)m0 * K_);
  const char* bp = (const char*)(Bm + (size_t)n0 * K_);

  const int KT = K_ >> 7;  // 128-wide K-steps
  for (int kt = 0; kt < KT; ++kt) {
#pragma unroll
    for (int i = 0; i < 8; ++i) {
      gload_lds16(ap + aoff[i], (char*)lA + ldo[i]);
      gload_lds16(bp + aoff[i], (char*)lB + ldo[i]);
    }
    ap += 256; bp += 256;
    __syncthreads();  // drains staging vmcnt
#pragma unroll
    for (int ks = 0; ks < 4; ++ks) {
      short8 af[4], bfr[4];
#pragma unroll
      for (int mt = 0; mt < 4; ++mt) {
        const int row = wr * 64 + mt * 16 + l15;
        const int byteoff = (ks * 64 + lhi * 16) ^ ((row & 15) << 4);
        af[mt] = *(const short8*)((const char*)lA + row * 256 + byteoff);
      }
#pragma unroll
      for (int nt = 0; nt < 4; ++nt) {
        const int row = wc * 64 + nt * 16 + l15;
        const int byteoff = (ks * 64 + lhi * 16) ^ ((row & 15) << 4);
        bfr[nt] = *(const short8*)((const char*)lB + row * 256 + byteoff);
      }
#pragma unroll
      for (int mt = 0; mt < 4; ++mt)
#pragma unroll
        for (int nt = 0; nt < 4; ++nt)
          acc[mt][nt] = __builtin_amdgcn_mfma_f32_16x16x32_bf16(af[mt], bfr[nt], acc[mt][nt], 0, 0, 0);
    }
    __syncthreads();  // safe to overwrite tile next iter
  }

#pragma unroll
  for (int mt = 0; mt < 4; ++mt) {
#pragma unroll
    for (int nt = 0; nt < 4; ++nt) {
      const int n = n0 + wc * 64 + nt * 16 + l15;
      const float bv = bias[n];
#pragma unroll
      for (int r = 0; r < 4; ++r) {
        const int m = m0 + wr * 64 + mt * 16 + lhi * 4 + r;
        float v = acc[mt][nt][r] + bv;
        if (MODE == 0 || MODE == 1) {
          if (MODE == 0) v *= 0.18033688011112042f;  // 0.125 * log2(e)
          const int b = m >> 11, t = m & 2047;
          const int h = n >> 6, dk = n & 63;
          ((unsigned short*)Cout)[(((size_t)(b * 16 + h) * 2048 + t) << 6) + dk] = f2bf(v);
        } else if (MODE == 2) {
          const int b = m >> 11, t = m & 2047;
          const int h = n >> 6, dv = n & 63;
          ((unsigned short*)Cout)[((size_t)((b * 16 + h) * 64 + dv) << 11) + t] = f2bf(v);
        } else {
          ((float*)Cout)[(size_t)m * 1024 + n] = v;
        }
      }
    }
  }
}

// flash attention (no-max softmax, exp2-domain): grid (T/256, B*H), 8 waves,
// 32 q rows per wave (2 subtiles of 16), disjoint lP per (wave, sub).
// T14 async-STAGE split (round-16 proven, 94us): K/V tile kb+1 loaded into
// REGISTERS at iteration top (compiler-managed waitcnt), full iteration of
// compute hides HBM latency, then barrier / ds_write / barrier.
__global__ __launch_bounds__(512, 2) void attn_kernel(
    const unsigned short* __restrict__ Qh, const unsigned short* __restrict__ Kh,
    const unsigned short* __restrict__ VTh, const unsigned long long* __restrict__ maskv,
    unsigned short* __restrict__ Xout) {
  __shared__ unsigned short lK[64 * 64];
  __shared__ unsigned short lVT[64 * 64];
  __shared__ unsigned short lP[8][2][16 * 64];
  const int tid = threadIdx.x, lane = tid & 63, wave = tid >> 6;
  const int l15 = lane & 15, lhi = lane >> 4;
  int qt, bh;
  xcd_remap(blockIdx.x, blockIdx.y, qt, bh);  // 8 q-tiles of a head -> 1 XCD
  const int b = bh >> 4, h = bh & 15;
  const int qbase = qt * 256 + wave * 32;  // wave's 32 q rows

  // Q fragments (B operand of swapped QK^T): Q[q=qbase+sub*16+l15][k=lhi*8+j]
  short8 qf[2][2];
#pragma unroll
  for (int sub = 0; sub < 2; ++sub) {
    const size_t qb = ((size_t)bh * 2048 + (qbase + sub * 16 + l15)) * 64 + lhi * 8;
    qf[sub][0] = *(const short8*)(Qh + qb);
    qf[sub][1] = *(const short8*)(Qh + qb + 32);
  }
  f32x4 oacc[2][4];  // O[sub][q=lhi*4+r][dv=nt*16+l15]
#pragma unroll
  for (int sub = 0; sub < 2; ++sub)
#pragma unroll
    for (int nt = 0; nt < 4; ++nt) oacc[sub][nt] = (f32x4)0.0f;
  f32x4 lacc0 = (f32x4)0.0f, lacc1 = (f32x4)0.0f;  // row sums via ones-col MFMA

  short8 ones8;
#pragma unroll
  for (int j = 0; j < 8; ++j) ones8[j] = (short)0x3F80;  // bf16 1.0

  // staging: one K chunk + one VT chunk per lane (512 lanes = 512 chunks each)
  const int cl = tid;  // chunk id
  const int crow = cl >> 3, cg = (cl & 7) ^ (crow & 7);
  const unsigned koff = (unsigned)(crow * 128 + cg * 16);   // K row-major [64][64]
  const unsigned voff = (unsigned)(crow * 4096 + cg * 16);  // VT row stride 2048 bf16
  char* const ldK = (char*)lK + tid * 16;   // same layout the DMA variant used
  char* const ldV = (char*)lVT + tid * 16;
  const char* kp = (const char*)(Kh + (size_t)bh * (2048 * 64));
  const char* vp = (const char*)(VTh + (size_t)bh * (64 * 2048));
  // readfirstlane keeps mask pointers provably wave-uniform (s_load -> SGPR
  // pairs, required by the "s" asm constraint below).
  const int wv = __builtin_amdgcn_readfirstlane(wave);
  const unsigned long long* mk0 =
      maskv + ((size_t)(b * 128 + qt * 16 + wv * 2) << 9);
  const unsigned long long* mk1 = mk0 + 512;

  // prologue: tile 0 via regs -> LDS (compiler inserts the vmcnt wait at the
  // register use inside the ds_write)
  {
    uint4 kreg = *(const uint4*)(kp + koff);
    uint4 vreg = *(const uint4*)(vp + voff);
    *(uint4*)ldK = kreg;
    *(uint4*)ldV = vreg;
  }
  __syncthreads();
  const char* kpn = kp + 8192;
  const char* vpn = vp + 128;

  const float ninf = __int_as_float(0xFF800000u);
  for (int kb = 0; kb < 32; ++kb) {
    // issue-early: next tile into registers; consumed only at the ds_write
    // after the end-of-iteration barrier -> full body hides HBM latency.
    uint4 kreg, vreg;
    if (kb < 31) {
      kreg = *(const uint4*)(kpn + koff);
      vreg = *(const uint4*)(vpn + voff);
      kpn += 8192; vpn += 128;
    }

    // S^T = K Q^T for both subtiles: each kf read feeds 2 MFMA.
    // lane holds S[sub][kv=nt*16+lhi*4+r][q=l15] (log2-domain)
    f32x4 s[2][4];
    __builtin_amdgcn_s_setprio(1);
#pragma unroll
    for (int nt = 0; nt < 4; ++nt) {
      f32x4 a0 = (f32x4)0.0f, a1 = (f32x4)0.0f;
#pragma unroll
      for (int ks = 0; ks < 2; ++ks) {
        const int row = nt * 16 + l15;
        const int byteoff = (ks * 64 + lhi * 16) ^ ((row & 7) << 4);
        short8 kf = *(const short8*)((const char*)lK + row * 128 + byteoff);
        a0 = __builtin_amdgcn_mfma_f32_16x16x32_bf16(kf, qf[0][ks], a0, 0, 0, 0);
        a1 = __builtin_amdgcn_mfma_f32_16x16x32_bf16(kf, qf[1][ks], a1, 0, 0, 0);
      }
      s[0][nt] = a0;
      s[1][nt] = a1;
    }
    __builtin_amdgcn_s_setprio(0);

    // mask-select (-inf) + exp2 + pack + P->LDS for BOTH subtiles (PV follows)
#pragma unroll
    for (int sub = 0; sub < 2; ++sub) {
      const unsigned long long* mk = (sub == 0) ? mk0 : mk1;
      uint2 pu[4];
#pragma unroll
      for (int nt = 0; nt < 4; ++nt) {
        float p0, p1, p2, p3;
        {
          float sm;
          asm("v_cndmask_b32 %0, %1, %2, %3"
              : "=v"(sm) : "v"(ninf), "v"(s[sub][nt][0]), "s"(mk[nt * 4 + 0]));
          p0 = __builtin_amdgcn_exp2f(sm);
          asm("v_cndmask_b32 %0, %1, %2, %3"
              : "=v"(sm) : "v"(ninf), "v"(s[sub][nt][1]), "s"(mk[nt * 4 + 1]));
          p1 = __builtin_amdgcn_exp2f(sm);
          asm("v_cndmask_b32 %0, %1, %2, %3"
              : "=v"(sm) : "v"(ninf), "v"(s[sub][nt][2]), "s"(mk[nt * 4 + 2]));
          p2 = __builtin_amdgcn_exp2f(sm);
          asm("v_cndmask_b32 %0, %1, %2, %3"
              : "=v"(sm) : "v"(ninf), "v"(s[sub][nt][3]), "s"(mk[nt * 4 + 3]));
          p3 = __builtin_amdgcn_exp2f(sm);
        }
        unsigned int lo, hi;
        asm("v_cvt_pk_bf16_f32 %0, %1, %2" : "=v"(lo) : "v"(p0), "v"(p1));
        asm("v_cvt_pk_bf16_f32 %0, %1, %2" : "=v"(hi) : "v"(p2), "v"(p3));
        pu[nt].x = lo;
        pu[nt].y = hi;
      }
      unsigned short* lPw = lP[wave][sub];
      {
        const int swz = (l15 & 7) << 4;
        char* rowp = (char*)lPw + l15 * 128;
#pragma unroll
        for (int nt = 0; nt < 4; ++nt)
          *(uint2*)(rowp + ((nt * 32 + lhi * 8) ^ swz)) = pu[nt];
      }
    }
    mk0 += 16;
    mk1 += 16;

    // PV: shared vf reads — each V fragment feeds both subtiles
    __builtin_amdgcn_s_setprio(1);
#pragma unroll
    for (int ks = 0; ks < 2; ++ks) {
      const int pbyte = (ks * 64 + lhi * 16) ^ ((l15 & 7) << 4);
      short8 pf0 = *(const short8*)((const char*)lP[wave][0] + l15 * 128 + pbyte);
      short8 pf1 = *(const short8*)((const char*)lP[wave][1] + l15 * 128 + pbyte);
      lacc0 = __builtin_amdgcn_mfma_f32_16x16x32_bf16(pf0, ones8, lacc0, 0, 0, 0);
      lacc1 = __builtin_amdgcn_mfma_f32_16x16x32_bf16(pf1, ones8, lacc1, 0, 0, 0);
#pragma unroll
      for (int nt = 0; nt < 4; ++nt) {
        const int vrow = nt * 16 + l15;
        const int vbyte = (ks * 64 + lhi * 16) ^ ((vrow & 7) << 4);
        short8 vf = *(const short8*)((const char*)lVT + vrow * 128 + vbyte);
        oacc[0][nt] = __builtin_amdgcn_mfma_f32_16x16x32_bf16(pf0, vf, oacc[0][nt], 0, 0, 0);
        oacc[1][nt] = __builtin_amdgcn_mfma_f32_16x16x32_bf16(pf1, vf, oacc[1][nt], 0, 0, 0);
      }
    }
    __builtin_amdgcn_s_setprio(0);

    if (kb < 31) {
      __syncthreads();     // all waves done READING tile kb
      *(uint4*)ldK = kreg; // write tile kb+1 (vmcnt wait auto-inserted here)
      *(uint4*)ldV = vreg;
      __syncthreads();     // writes visible to all waves
    }
  }

#pragma unroll
  for (int sub = 0; sub < 2; ++sub) {
#pragma unroll
    for (int r = 0; r < 4; ++r) {
      const float l = (sub == 0) ? lacc0[r] : lacc1[r];
      const float inv = l > 0.0f ? 1.0f / l : 0.0f;
      const int t = qbase + sub * 16 + lhi * 4 + r;
      unsigned short* dst = Xout + ((size_t)(b * 2048 + t)) * 1024 + h * 64;
#pragma unroll
      for (int nt = 0; nt < 4; ++nt) dst[nt * 16 + l15] = f2bf(oacc[sub][nt][r] * inv);
    }
  }
}

extern "C" void kernel_launch(void* const* d_in, const int* in_sizes, int n_in,
                              void* d_out, int out_size, void* d_ws, size_t ws_size,
                              hipStream_t stream) {
  const float* query = (const float*)d_in[0];
  const float* key = (const float*)d_in[1];
  const float* value = (const float*)d_in[2];
  const int* mask = (const int*)d_in[3];
  const float* Wq = (const float*)d_in[4];
  const float* bq = (const float*)d_in[5];
  const float* Wk = (const float*)d_in[6];
  const float* bk = (const float*)d_in[7];
  const float* Wv = (const float*)d_in[8];
  const float* bv = (const float*)d_in[9];
  const float* Wo = (const float*)d_in[10];
  const float* bo = (const float*)d_in[11];
  float* out = (float*)d_out;

  char* ws = (char*)d_ws;
  size_t off = 0;
  auto alloc = [&](size_t bytes) {
    char* p = ws + off;
    off += (bytes + 255) & ~(size_t)255;
    return p;
  };
  const size_t NE = (size_t)B_ * T_ * D_;  // 8388608
  unsigned short* qb = (unsigned short*)alloc(NE * 2);  // also reused as X
  unsigned short* kb = (unsigned short*)alloc(NE * 2);
  unsigned short* vb = (unsigned short*)alloc(NE * 2);
  unsigned short* wqb = (unsigned short*)alloc((size_t)1024 * 1024 * 2);
  unsigned short* wkb = (unsigned short*)alloc((size_t)1024 * 1024 * 2);
  unsigned short* wvb = (unsigned short*)alloc((size_t)1024 * 1024 * 2);
  unsigned short* wob = (unsigned short*)alloc((size_t)1024 * 1024 * 2);
  unsigned short* Qh = (unsigned short*)alloc(NE * 2);
  unsigned short* Kh = (unsigned short*)alloc(NE * 2);
  unsigned short* VTh = (unsigned short*)alloc(NE * 2);
  unsigned long long* pmw = (unsigned long long*)alloc((size_t)B_ * 32 * 4 * 512 * 8);

  // all fp32 -> bf16 conversions in one flat launch (7340032 float4s)
  cvt_all<<<28672, 256, 0, stream>>>(query, key, value, Wq, Wk, Wv, Wo,
                                     qb, kb, vb, wqb, wkb, wvb, wob);
  // mask -> wave-shaped vcc u64s
  dim3 pgrid(32, 4, 2);
  pack_mask_v<<<pgrid, 256, 0, stream>>>(mask, pmw);

  const int M = B_ * T_;  // 8192
  dim3 ggrid(8, 64);
  gemm_bt<0><<<ggrid, 256, 0, stream>>>(qb, wqb, bq, Qh, M, 1024);
  gemm_bt<1><<<ggrid, 256, 0, stream>>>(kb, wkb, bk, Kh, M, 1024);
  gemm_bt<2><<<ggrid, 256, 0, stream>>>(vb, wvb, bv, VTh, M, 1024);

  dim3 agrid(T_ / 256, B_ * H_);
  attn_kernel<<<agrid, 512, 0, stream>>>(Qh, Kh, VTh, pmw, qb);

  dim3 ogrid(8, 64);
  gemm_bt<3><<<ogrid, 256, 0, stream>>>(qb, wob, bo, out, M, 1024);
}